// Round 11
// baseline (309.322 us; speedup 1.0000x reference)
//
#include <hip/hip_runtime.h>
#include <hip/hip_fp16.h>

#define FDIM 256
#define ALPHA 0.2f

typedef _Float16 half8 __attribute__((ext_vector_type(8)));
typedef float floatx4 __attribute__((ext_vector_type(4)));

// ---- prep W (fp16 chunked W^T image) + edge histogram, fused ---------------
__global__ __launch_bounds__(256) void prep_hist(const float* __restrict__ W,
                                                 _Float16* __restrict__ wswz,
                                                 const int* __restrict__ edge,
                                                 int* __restrict__ deg, int E) {
  if (blockIdx.x < 32) {
    const int g = blockIdx.x * 256 + threadIdx.x;  // 0..8191
    const int kc = g >> 11, L = g & 2047;
    const int n = L >> 3, c = L & 7;
    half8 hv;
#pragma unroll
    for (int j = 0; j < 8; ++j)
      hv[j] = (_Float16)W[(size_t)(kc * 64 + c * 8 + j) * 256 + n];
    *(half8*)(wswz + (size_t)g * 8) = hv;
  } else {
    const int e = (blockIdx.x - 32) * 256 + threadIdx.x;
    if (e < E) atomicAdd(&deg[edge[e]], 1);
  }
}

// ---- GEMM h = x@W: full-K A-stage (one barrier), 8-step MFMA loop ----------
#define HT_STRIDE 264
__global__ __launch_bounds__(256) void gemm_mfma(
    const float* __restrict__ x, const _Float16* __restrict__ wswz,
    const float* __restrict__ a, _Float16* __restrict__ h,
    float* __restrict__ s, float* __restrict__ t, int M) {
  __shared__ __align__(16) _Float16 smem[64 * HT_STRIDE];  // 33.8 KB
  _Float16* As = smem;  // 64*256 halves = 32 KB staging
  const int tid = threadIdx.x;
  const int w = tid >> 6, l = tid & 63;
  const int l15 = l & 15, q = l >> 4;
  const int row0 = blockIdx.x * 64;

  floatx4 acc[4][4];
#pragma unroll
  for (int mt = 0; mt < 4; ++mt)
#pragma unroll
    for (int nt = 0; nt < 4; ++nt) acc[mt][nt] = (floatx4){0.f, 0.f, 0.f, 0.f};

#pragma unroll
  for (int kc = 0; kc < 4; ++kc)
#pragma unroll
    for (int hf = 0; hf < 2; ++hf) {
      const int id = hf * 256 + tid;  // 0..511
      const int m = id >> 3;
      const int c = (id & 7) ^ (m & 7);
      const int row = row0 + m;
      float4 f0 = make_float4(0.f, 0.f, 0.f, 0.f);
      float4 f1 = make_float4(0.f, 0.f, 0.f, 0.f);
      if (row < M) {
        const float4* p =
            (const float4*)(x + (size_t)row * 256 + kc * 64 + c * 8);
        f0 = p[0];
        f1 = p[1];
      }
      half8 hv;
      hv[0] = (_Float16)f0.x; hv[1] = (_Float16)f0.y;
      hv[2] = (_Float16)f0.z; hv[3] = (_Float16)f0.w;
      hv[4] = (_Float16)f1.x; hv[5] = (_Float16)f1.y;
      hv[6] = (_Float16)f1.z; hv[7] = (_Float16)f1.w;
      *(half8*)(As + (size_t)(kc * 512 + id) * 8) = hv;
    }
  __syncthreads();

#pragma unroll 2
  for (int ks = 0; ks < 8; ++ks) {
    const int kc = ks >> 1;
    const int c = (ks & 1) * 4 + q;
    half8 bf[4];
#pragma unroll
    for (int nt = 0; nt < 4; ++nt) {
      const int n = w * 64 + nt * 16 + l15;
      bf[nt] = *(const half8*)(wswz + (size_t)(kc * 2048 + n * 8 + c) * 8);
    }
    half8 af[4];
#pragma unroll
    for (int mt = 0; mt < 4; ++mt) {
      const int m = mt * 16 + l15;
      af[mt] =
          *(const half8*)(As + (size_t)(kc * 512 + m * 8 + (c ^ (m & 7))) * 8);
    }
#pragma unroll
    for (int mt = 0; mt < 4; ++mt)
#pragma unroll
      for (int nt = 0; nt < 4; ++nt)
        acc[mt][nt] = __builtin_amdgcn_mfma_f32_16x16x32_f16(
            af[mt], bf[nt], acc[mt][nt], 0, 0, 0);
  }
  __syncthreads();

  // epilogue: C/D -> LDS row-major -> coalesced 16B stores
#pragma unroll
  for (int mt = 0; mt < 4; ++mt)
#pragma unroll
    for (int nt = 0; nt < 4; ++nt)
#pragma unroll
      for (int r = 0; r < 4; ++r)
        smem[(size_t)(mt * 16 + q * 4 + r) * HT_STRIDE + w * 64 + nt * 16 +
             l15] = (_Float16)acc[mt][nt][r];
  __syncthreads();

  const int w8 = tid >> 5;
  const int colh = (tid & 31) * 8;
#pragma unroll
  for (int p = 0; p < 8; ++p) {
    const int rl = p * 8 + w8;
    const int row = row0 + rl;
    if (row < M)
      *(half8*)(h + (size_t)row * 256 + colh) =
          *(const half8*)(smem + (size_t)rl * HT_STRIDE + colh);
  }

  // s/t from LDS tile
  const int r8 = tid >> 2, seg = tid & 3;
  float sp = 0.f, tp = 0.f;
#pragma unroll
  for (int c8 = 0; c8 < 8; ++c8) {
    const int col = seg * 64 + c8 * 8;
    const half8 hv = *(const half8*)(smem + (size_t)r8 * HT_STRIDE + col);
    const float4 a0 = *(const float4*)(a + col);
    const float4 a1 = *(const float4*)(a + col + 4);
    const float4 b0 = *(const float4*)(a + 256 + col);
    const float4 b1 = *(const float4*)(a + 256 + col + 4);
    sp += (float)hv[0] * a0.x + (float)hv[1] * a0.y + (float)hv[2] * a0.z +
          (float)hv[3] * a0.w + (float)hv[4] * a1.x + (float)hv[5] * a1.y +
          (float)hv[6] * a1.z + (float)hv[7] * a1.w;
    tp += (float)hv[0] * b0.x + (float)hv[1] * b0.y + (float)hv[2] * b0.z +
          (float)hv[3] * b0.w + (float)hv[4] * b1.x + (float)hv[5] * b1.y +
          (float)hv[6] * b1.z + (float)hv[7] * b1.w;
  }
  sp += __shfl_xor(sp, 1);
  sp += __shfl_xor(sp, 2);
  tp += __shfl_xor(tp, 1);
  tp += __shfl_xor(tp, 2);
  if (seg == 0 && row0 + r8 < M) {
    s[row0 + r8] = sp;
    t[row0 + r8] = tp;
  }
}

// ---- scan phase 1: per-block exclusive scan + block sums -------------------
__global__ __launch_bounds__(1024) void scan1(const int* __restrict__ deg,
                                              int* __restrict__ rowstart,
                                              int* __restrict__ bsum, int n) {
  const int tid = threadIdx.x;
  const int i = blockIdx.x * 1024 + tid;
  const int val = (i < n) ? deg[i] : 0;
  const int lane = tid & 63, wv = tid >> 6;
  int v = val;
#pragma unroll
  for (int off = 1; off < 64; off <<= 1) {
    const int o = __shfl_up(v, off);
    if (lane >= off) v += o;
  }
  __shared__ int wsum[16];
  __shared__ int woff[16];
  if (lane == 63) wsum[wv] = v;
  __syncthreads();
  if (tid < 16) {
    int wv2 = wsum[tid];
#pragma unroll
    for (int off = 1; off < 16; off <<= 1) {
      const int o = __shfl_up(wv2, off);
      if (tid >= off) wv2 += o;
    }
    woff[tid] = wv2;
  }
  __syncthreads();
  const int incl = v + (wv ? woff[wv - 1] : 0);
  if (i < n) rowstart[i] = incl - val;
  if (tid == 1023) bsum[blockIdx.x] = woff[15];
}

// ---- scan phase 2+3 fused: each block redundantly reduces bsum prefix ------
__global__ __launch_bounds__(1024) void scan3(int* __restrict__ rowstart,
                                              int* __restrict__ rsc,
                                              const int* __restrict__ bsum,
                                              int n, int nb) {
  __shared__ int sboff;
  const int tid = threadIdx.x;
  if (tid < 64) {
    const int v = (tid < nb) ? bsum[tid] : 0;
    int pre = (tid < (int)blockIdx.x) ? v : 0;
    int tot = v;
#pragma unroll
    for (int off = 32; off > 0; off >>= 1) {
      pre += __shfl_xor(pre, off);
      tot += __shfl_xor(tot, off);
    }
    if (tid == 0) {
      sboff = pre;
      if (blockIdx.x == (unsigned)(nb - 1)) rowstart[n] = tot;
    }
  }
  __syncthreads();
  const int i = blockIdx.x * 1024 + tid;
  if (i < n) {
    const int v = rowstart[i] + sboff;
    rowstart[i] = v;
    rsc[i] = v;
  }
}

// ---- scatter: pure CSR permutation (4B payload) ----------------------------
__global__ void scatter_kernel(const int* __restrict__ edge,
                               int* __restrict__ rsc, int* __restrict__ sdst,
                               int E) {
  const int e = blockIdx.x * 256 + threadIdx.x;
  if (e < E) {
    const int src = edge[e];
    const int dst = edge[E + e];
    const int pos = atomicAdd(&rsc[src], 1);
    sdst[pos] = dst;
  }
}

// ---- aggregation: wave = 2 edges/iter, lane = 8 features; row-range split --
__global__ __launch_bounds__(256) void agg_kernel(
    const _Float16* __restrict__ h, const float* __restrict__ s,
    const float* __restrict__ t, const int* __restrict__ rowstart,
    const int* __restrict__ sdst, float* __restrict__ out, int rowbase,
    int rowlim) {
  const int w = threadIdx.x >> 6, l = threadIdx.x & 63;
  const int row = rowbase + blockIdx.x * 4 + w;
  if (row >= rowlim) return;
  const int start = rowstart[row], end = rowstart[row + 1];
  const float srow = s[row];
  const int half = l >> 5;
  const int lh = l & 31;
  const size_t fo = (size_t)lh * 8;
  float acc[8] = {};
  float rs = 0.f;
  int j = start;
  for (; j + 8 <= end; j += 8) {
#pragma unroll
    for (int u = 0; u < 4; ++u) {
      const int d = sdst[j + u * 2 + half];
      const float logit = srow + t[d];
      const float lr = logit > 0.f ? logit : ALPHA * logit;
      const float e = __expf(-lr);
      const half8 v = *(const half8*)(h + (size_t)d * 256 + fo);
      rs += e;
#pragma unroll
      for (int k = 0; k < 8; ++k) acc[k] += e * (float)v[k];
    }
  }
  for (; j < end; j += 2) {
    const int idx = j + half;
    const bool valid = idx < end;
    const int d = valid ? sdst[idx] : 0;
    const float logit = srow + t[d];
    const float lr = logit > 0.f ? logit : ALPHA * logit;
    const float e = valid ? __expf(-lr) : 0.f;
    const half8 v = *(const half8*)(h + (size_t)d * 256 + fo);
    rs += e;
#pragma unroll
    for (int k = 0; k < 8; ++k) acc[k] += e * (float)v[k];
  }
  rs += __shfl_xor(rs, 32);
#pragma unroll
  for (int k = 0; k < 8; ++k) acc[k] += __shfl_xor(acc[k], 32);
  const float inv = 1.f / rs;
  float4 o;
#pragma unroll
  for (int k = 0; k < 4; ++k) {
    const float vv = acc[half * 4 + k] * inv;
    (&o.x)[k] = vv > 0.f ? vv : 0.f;
  }
  *(float4*)(out + (size_t)row * 256 + lh * 8 + half * 4) = o;
}

extern "C" void kernel_launch(void* const* d_in, const int* in_sizes, int n_in,
                              void* d_out, int out_size, void* d_ws,
                              size_t ws_size, hipStream_t stream) {
  const float* x = (const float*)d_in[0];
  const int* edge = (const int*)d_in[1];
  const float* W = (const float*)d_in[2];
  const float* a = (const float*)d_in[3];
  float* out = (float*)d_out;
  const int N = in_sizes[0] / FDIM;  // 50000
  const int E = in_sizes[1] / 2;     // 850000
  const int NB = (N + 1023) / 1024;  // 49

  _Float16* h = (_Float16*)d_ws;          // N*256 fp16
  _Float16* wswz = h + (size_t)N * FDIM;  // 65536 halves (128 KB)
  float* s = (float*)(wswz + 8192 * 8);   // N
  float* t = s + N;                       // N
  int* deg = (int*)(t + N);               // N
  int* rsc = deg + N;                     // N
  int* rowstart = rsc + N;                // N+2
  int* bsum = rowstart + N + 2;           // 64
  int* sdst = bsum + 64;                  // E

  hipMemsetAsync(deg, 0, (size_t)N * sizeof(int), stream);

  prep_hist<<<32 + (E + 255) / 256, 256, 0, stream>>>(W, wswz, edge, deg, E);
  gemm_mfma<<<(N + 63) / 64, 256, 0, stream>>>(x, wswz, a, h, s, t, N);
  scan1<<<NB, 1024, 0, stream>>>(deg, rowstart, bsum, N);
  scan3<<<NB, 1024, 0, stream>>>(rowstart, rsc, bsum, N, NB);
  scatter_kernel<<<(E + 255) / 256, 256, 0, stream>>>(edge, rsc, sdst, E);
  // agg split into 4 row-range dispatches (diagnostic: lowers top-5 cutoff)
  const int QR = (N + 3) / 4;  // rows per quarter
  for (int qtr = 0; qtr < 4; ++qtr) {
    const int rb = qtr * QR;
    const int rl = (qtr == 3) ? N : (rb + QR);
    const int nblk = (rl - rb + 3) / 4;
    agg_kernel<<<nblk, 256, 0, stream>>>(h, s, t, rowstart, sdst, out, rb, rl);
  }
}

// Round 12
// 273.698 us; speedup vs baseline: 1.1302x; 1.1302x over previous
//
#include <hip/hip_runtime.h>
#include <hip/hip_fp16.h>

#define FDIM 256
#define ALPHA 0.2f

typedef _Float16 half8 __attribute__((ext_vector_type(8)));
typedef float floatx4 __attribute__((ext_vector_type(4)));

// ---- prep W (fp16 chunked W^T image) + edge histogram (4 edges/thread) -----
__global__ __launch_bounds__(256) void prep_hist(const float* __restrict__ W,
                                                 _Float16* __restrict__ wswz,
                                                 const int* __restrict__ edge,
                                                 int* __restrict__ deg, int E) {
  if (blockIdx.x < 32) {
    const int g = blockIdx.x * 256 + threadIdx.x;  // 0..8191
    const int kc = g >> 11, L = g & 2047;
    const int n = L >> 3, c = L & 7;
    half8 hv;
#pragma unroll
    for (int j = 0; j < 8; ++j)
      hv[j] = (_Float16)W[(size_t)(kc * 64 + c * 8 + j) * 256 + n];
    *(half8*)(wswz + (size_t)g * 8) = hv;
  } else {
    const int base = (blockIdx.x - 32) * 1024 + threadIdx.x;
    int srcs[4];
#pragma unroll
    for (int u = 0; u < 4; ++u) {
      const int e = base + u * 256;
      srcs[u] = (e < E) ? edge[e] : -1;
    }
#pragma unroll
    for (int u = 0; u < 4; ++u)
      if (srcs[u] >= 0) atomicAdd(&deg[srcs[u]], 1);
  }
}

// ---- fused: scatter (latency-bound) + GEMM (MFMA-bound) co-scheduled -------
#define HT_STRIDE 264
__global__ __launch_bounds__(256) void gemm_scatter(
    const float* __restrict__ x, const _Float16* __restrict__ wswz,
    const float* __restrict__ a, _Float16* __restrict__ h,
    float* __restrict__ s, float* __restrict__ t, int M,
    const int* __restrict__ edge, int* __restrict__ rsc,
    int* __restrict__ sdst, int E, int SB) {
  __shared__ __align__(16) _Float16 smem[64 * HT_STRIDE];  // 33.8 KB
  const int tid = threadIdx.x;

  if ((int)blockIdx.x < SB) {
    // ---- scatter path: 1024 edges/block, 4 per thread (4x atomic MLP) ----
    const int base = blockIdx.x * 1024 + tid;
    int srcs[4], dsts[4];
#pragma unroll
    for (int u = 0; u < 4; ++u) {
      const int e = base + u * 256;
      if (e < E) {
        srcs[u] = edge[e];
        dsts[u] = edge[E + e];
      } else {
        srcs[u] = -1;
      }
    }
    int pos[4];
#pragma unroll
    for (int u = 0; u < 4; ++u)
      if (srcs[u] >= 0) pos[u] = atomicAdd(&rsc[srcs[u]], 1);
#pragma unroll
    for (int u = 0; u < 4; ++u)
      if (srcs[u] >= 0) sdst[pos[u]] = dsts[u];
    return;
  }

  // ---- gemm path -------------------------------------------------------
  _Float16* As = smem;
  const int w = tid >> 6, l = tid & 63;
  const int l15 = l & 15, q = l >> 4;
  const int row0 = (blockIdx.x - SB) * 64;

  floatx4 acc[4][4];
#pragma unroll
  for (int mt = 0; mt < 4; ++mt)
#pragma unroll
    for (int nt = 0; nt < 4; ++nt) acc[mt][nt] = (floatx4){0.f, 0.f, 0.f, 0.f};

#pragma unroll
  for (int kc = 0; kc < 4; ++kc)
#pragma unroll
    for (int hf = 0; hf < 2; ++hf) {
      const int id = hf * 256 + tid;  // 0..511
      const int m = id >> 3;
      const int c = (id & 7) ^ (m & 7);
      const int row = row0 + m;
      float4 f0 = make_float4(0.f, 0.f, 0.f, 0.f);
      float4 f1 = make_float4(0.f, 0.f, 0.f, 0.f);
      if (row < M) {
        const float4* p =
            (const float4*)(x + (size_t)row * 256 + kc * 64 + c * 8);
        f0 = p[0];
        f1 = p[1];
      }
      half8 hv;
      hv[0] = (_Float16)f0.x; hv[1] = (_Float16)f0.y;
      hv[2] = (_Float16)f0.z; hv[3] = (_Float16)f0.w;
      hv[4] = (_Float16)f1.x; hv[5] = (_Float16)f1.y;
      hv[6] = (_Float16)f1.z; hv[7] = (_Float16)f1.w;
      *(half8*)(As + (size_t)(kc * 512 + id) * 8) = hv;
    }
  __syncthreads();

#pragma unroll 2
  for (int ks = 0; ks < 8; ++ks) {
    const int kc = ks >> 1;
    const int c = (ks & 1) * 4 + q;
    half8 bf[4];
#pragma unroll
    for (int nt = 0; nt < 4; ++nt) {
      const int n = w * 64 + nt * 16 + l15;
      bf[nt] = *(const half8*)(wswz + (size_t)(kc * 2048 + n * 8 + c) * 8);
    }
    half8 af[4];
#pragma unroll
    for (int mt = 0; mt < 4; ++mt) {
      const int m = mt * 16 + l15;
      af[mt] =
          *(const half8*)(As + (size_t)(kc * 512 + m * 8 + (c ^ (m & 7))) * 8);
    }
#pragma unroll
    for (int mt = 0; mt < 4; ++mt)
#pragma unroll
      for (int nt = 0; nt < 4; ++nt)
        acc[mt][nt] = __builtin_amdgcn_mfma_f32_16x16x32_f16(
            af[mt], bf[nt], acc[mt][nt], 0, 0, 0);
  }
  __syncthreads();

  // epilogue: C/D -> LDS row-major -> coalesced 16B stores
#pragma unroll
  for (int mt = 0; mt < 4; ++mt)
#pragma unroll
    for (int nt = 0; nt < 4; ++nt)
#pragma unroll
      for (int r = 0; r < 4; ++r)
        smem[(size_t)(mt * 16 + q * 4 + r) * HT_STRIDE + w * 64 + nt * 16 +
             l15] = (_Float16)acc[mt][nt][r];
  __syncthreads();

  const int w8 = tid >> 5;
  const int colh = (tid & 31) * 8;
#pragma unroll
  for (int p = 0; p < 8; ++p) {
    const int rl = p * 8 + w8;
    const int row = row0 + rl;
    if (row < M)
      *(half8*)(h + (size_t)row * 256 + colh) =
          *(const half8*)(smem + (size_t)rl * HT_STRIDE + colh);
  }

  // s/t from LDS tile
  const int r8 = tid >> 2, seg = tid & 3;
  float sp = 0.f, tp = 0.f;
#pragma unroll
  for (int c8 = 0; c8 < 8; ++c8) {
    const int col = seg * 64 + c8 * 8;
    const half8 hv = *(const half8*)(smem + (size_t)r8 * HT_STRIDE + col);
    const float4 a0 = *(const float4*)(a + col);
    const float4 a1 = *(const float4*)(a + col + 4);
    const float4 b0 = *(const float4*)(a + 256 + col);
    const float4 b1 = *(const float4*)(a + 256 + col + 4);
    sp += (float)hv[0] * a0.x + (float)hv[1] * a0.y + (float)hv[2] * a0.z +
          (float)hv[3] * a0.w + (float)hv[4] * a1.x + (float)hv[5] * a1.y +
          (float)hv[6] * a1.z + (float)hv[7] * a1.w;
    tp += (float)hv[0] * b0.x + (float)hv[1] * b0.y + (float)hv[2] * b0.z +
          (float)hv[3] * b0.w + (float)hv[4] * b1.x + (float)hv[5] * b1.y +
          (float)hv[6] * b1.z + (float)hv[7] * b1.w;
  }
  sp += __shfl_xor(sp, 1);
  sp += __shfl_xor(sp, 2);
  tp += __shfl_xor(tp, 1);
  tp += __shfl_xor(tp, 2);
  if (seg == 0 && row0 + r8 < M) {
    s[row0 + r8] = sp;
    t[row0 + r8] = tp;
  }
}

// ---- scan phase 1: per-block exclusive scan + block sums -------------------
__global__ __launch_bounds__(1024) void scan1(const int* __restrict__ deg,
                                              int* __restrict__ rowstart,
                                              int* __restrict__ bsum, int n) {
  const int tid = threadIdx.x;
  const int i = blockIdx.x * 1024 + tid;
  const int val = (i < n) ? deg[i] : 0;
  const int lane = tid & 63, wv = tid >> 6;
  int v = val;
#pragma unroll
  for (int off = 1; off < 64; off <<= 1) {
    const int o = __shfl_up(v, off);
    if (lane >= off) v += o;
  }
  __shared__ int wsum[16];
  __shared__ int woff[16];
  if (lane == 63) wsum[wv] = v;
  __syncthreads();
  if (tid < 16) {
    int wv2 = wsum[tid];
#pragma unroll
    for (int off = 1; off < 16; off <<= 1) {
      const int o = __shfl_up(wv2, off);
      if (tid >= off) wv2 += o;
    }
    woff[tid] = wv2;
  }
  __syncthreads();
  const int incl = v + (wv ? woff[wv - 1] : 0);
  if (i < n) rowstart[i] = incl - val;
  if (tid == 1023) bsum[blockIdx.x] = woff[15];
}

// ---- scan phase 2+3 fused: each block redundantly reduces bsum prefix ------
__global__ __launch_bounds__(1024) void scan3(int* __restrict__ rowstart,
                                              int* __restrict__ rsc,
                                              const int* __restrict__ bsum,
                                              int n, int nb) {
  __shared__ int sboff;
  const int tid = threadIdx.x;
  if (tid < 64) {
    const int v = (tid < nb) ? bsum[tid] : 0;
    int pre = (tid < (int)blockIdx.x) ? v : 0;
    int tot = v;
#pragma unroll
    for (int off = 32; off > 0; off >>= 1) {
      pre += __shfl_xor(pre, off);
      tot += __shfl_xor(tot, off);
    }
    if (tid == 0) {
      sboff = pre;
      if (blockIdx.x == (unsigned)(nb - 1)) rowstart[n] = tot;
    }
  }
  __syncthreads();
  const int i = blockIdx.x * 1024 + tid;
  if (i < n) {
    const int v = rowstart[i] + sboff;
    rowstart[i] = v;
    rsc[i] = v;
  }
}

// ---- aggregation: wave = 2 edges/iter, lane = 8 features -------------------
__global__ __launch_bounds__(256) void agg_kernel(
    const _Float16* __restrict__ h, const float* __restrict__ s,
    const float* __restrict__ t, const int* __restrict__ rowstart,
    const int* __restrict__ sdst, float* __restrict__ out, int n) {
  const int w = threadIdx.x >> 6, l = threadIdx.x & 63;
  const int row = blockIdx.x * 4 + w;
  if (row >= n) return;
  const int start = rowstart[row], end = rowstart[row + 1];
  const float srow = s[row];
  const int half = l >> 5;
  const int lh = l & 31;
  const size_t fo = (size_t)lh * 8;
  float acc[8] = {};
  float rs = 0.f;
  int j = start;
  for (; j + 8 <= end; j += 8) {
#pragma unroll
    for (int u = 0; u < 4; ++u) {
      const int d = sdst[j + u * 2 + half];
      const float logit = srow + t[d];
      const float lr = logit > 0.f ? logit : ALPHA * logit;
      const float e = __expf(-lr);
      const half8 v = *(const half8*)(h + (size_t)d * 256 + fo);
      rs += e;
#pragma unroll
      for (int k = 0; k < 8; ++k) acc[k] += e * (float)v[k];
    }
  }
  for (; j < end; j += 2) {
    const int idx = j + half;
    const bool valid = idx < end;
    const int d = valid ? sdst[idx] : 0;
    const float logit = srow + t[d];
    const float lr = logit > 0.f ? logit : ALPHA * logit;
    const float e = valid ? __expf(-lr) : 0.f;
    const half8 v = *(const half8*)(h + (size_t)d * 256 + fo);
    rs += e;
#pragma unroll
    for (int k = 0; k < 8; ++k) acc[k] += e * (float)v[k];
  }
  rs += __shfl_xor(rs, 32);
#pragma unroll
  for (int k = 0; k < 8; ++k) acc[k] += __shfl_xor(acc[k], 32);
  const float inv = 1.f / rs;
  float4 o;
#pragma unroll
  for (int k = 0; k < 4; ++k) {
    const float vv = acc[half * 4 + k] * inv;
    (&o.x)[k] = vv > 0.f ? vv : 0.f;
  }
  *(float4*)(out + (size_t)row * 256 + lh * 8 + half * 4) = o;
}

extern "C" void kernel_launch(void* const* d_in, const int* in_sizes, int n_in,
                              void* d_out, int out_size, void* d_ws,
                              size_t ws_size, hipStream_t stream) {
  const float* x = (const float*)d_in[0];
  const int* edge = (const int*)d_in[1];
  const float* W = (const float*)d_in[2];
  const float* a = (const float*)d_in[3];
  float* out = (float*)d_out;
  const int N = in_sizes[0] / FDIM;  // 50000
  const int E = in_sizes[1] / 2;     // 850000
  const int NB = (N + 1023) / 1024;  // 49

  _Float16* h = (_Float16*)d_ws;          // N*256 fp16
  _Float16* wswz = h + (size_t)N * FDIM;  // 65536 halves (128 KB)
  float* s = (float*)(wswz + 8192 * 8);   // N
  float* t = s + N;                       // N
  int* deg = (int*)(t + N);               // N
  int* rsc = deg + N;                     // N
  int* rowstart = rsc + N;                // N+2
  int* bsum = rowstart + N + 2;           // 64
  int* sdst = bsum + 64;                  // E

  hipMemsetAsync(deg, 0, (size_t)N * sizeof(int), stream);

  const int EB = (E + 1023) / 1024;  // edge blocks (4 edges/thread)
  prep_hist<<<32 + EB, 256, 0, stream>>>(W, wswz, edge, deg, E);
  scan1<<<NB, 1024, 0, stream>>>(deg, rowstart, bsum, N);
  scan3<<<NB, 1024, 0, stream>>>(rowstart, rsc, bsum, N, NB);
  // fused: scatter blocks [0, EB) + gemm blocks [EB, EB + (N+63)/64)
  const int GB = (N + 63) / 64;
  gemm_scatter<<<EB + GB, 256, 0, stream>>>(x, wswz, a, h, s, t, N, edge, rsc,
                                            sdst, E, EB);
  agg_kernel<<<(N + 3) / 4, 256, 0, stream>>>(h, s, t, rowstart, sdst, out, N);
}